// Round 16
// baseline (177.746 us; speedup 1.0000x reference)
//
#include <hip/hip_runtime.h>

// Problem dims
#define TT 32
#define BB 8
#define DD 512
#define HH 512
#define RR 32
#define OO 512
#define H2 1024

typedef unsigned int uint;

// d_ws float-index offsets
#define OFF_WX    0        // [TT*BB][H2]   262144  (pre-LN then LN'd in place)
#define OFF_COLV  393216   // [2][BB][H2]    16384  (coherent Wh exchange)
#define OFF_FLAGS 409600   // 256 u32 barrier flags

#define AGENT __HIP_MEMORY_SCOPE_AGENT
#define RLX   __ATOMIC_RELAXED

#define HMW_P 528   // 528 % 32 == 16 -> hmw LDS accesses are exact 2-way (free)

__device__ __forceinline__ void st_coh(float* p, float v) {
  __hip_atomic_store(p, v, RLX, AGENT);
}
__device__ __forceinline__ float ld_coh(const float* p) {
  return __hip_atomic_load(const_cast<float*>(p), RLX, AGENT);
}
__device__ __forceinline__ float d4(const float4& a, const float4& b) {
  return a.x*b.x + a.y*b.y + a.z*b.z + a.w*b.w;
}

// ---------------- fused state-update + plast + Wh GEMV -> coherent post ----------------
// Row mapping: il = tid>>5 (row 0..15 of block), m = tid&31, elem j = 4*(m+32q)+c.
template<bool UPDATE>
__device__ __forceinline__ void gemv_step(
    int gi, int m,
    float4 (&dUr)[4], float4 (&tEr)[4],
    const float4 (&Wdvr)[4], const float4 (&wlo)[4],
    const float4 (&upr)[4], const float4 (&lor)[4],
    float s_b, float c1t, float c2t, float a_sp, float hbl, float hbh,
    const float* nh_s, const float* te_s,
    float* post)  // colvG + parity*BB*H2 + b*H2
{
  const float nh_i = nh_s[gi];
  const float te_i = UPDATE ? te_s[gi] : 0.0f;
  const float4* nh4 = reinterpret_cast<const float4*>(nh_s);
  const float4* te4 = reinterpret_cast<const float4*>(te_s);
  float plast = 0.0f, gdv = 0.0f, glo = 0.0f;
#pragma unroll
  for (int q = 0; q < 4; ++q) {
    const int J = m + 32*q;
    const float4 h4 = nh4[J];
    if (UPDATE) {
      const float4 t4 = te4[J];
#define SGRU_UPD(C) { \
      float o   = nh_i * t4.C - h4.C * te_i;                /* outer - outer^T    */ \
      float tEn = tEr[q].C + s_b * (o - tEr[q].C);          /* (1-s)tE + s*o      */ \
      tEr[q].C  = tEn;                                                               \
      float d   = c1t * dUr[q].C + c2t * tEn;               /* (1-tau)dU+tau*m*tE */ \
      d = fminf(d, upr[q].C); d = fmaxf(d, lor[q].C);       /* clip               */ \
      dUr[q].C  = d;                                                                 \
      plast = fmaf(d, h4.C, plast); }
      SGRU_UPD(x) SGRU_UPD(y) SGRU_UPD(z) SGRU_UPD(w)
#undef SGRU_UPD
    } else {
      plast += d4(dUr[q], h4);
    }
    gdv += d4(Wdvr[q], h4);
    glo += d4(wlo[q],  h4);
  }
#pragma unroll
  for (int off = 16; off >= 1; off >>= 1) {
    plast += __shfl_xor(plast, off);
    gdv   += __shfl_xor(gdv, off);
    glo   += __shfl_xor(glo, off);
  }
  if (m == 0) {
    st_coh(&post[gi],      glo + hbl);                    // low col gi
    st_coh(&post[HH + gi], gdv + hbh + a_sp * plast);     // high col HH+gi
  }
}

// ---------------- persistent recurrent kernel: 1 barrier/step, gather-hidden decode ----------------
__global__ __launch_bounds__(512, 1) void sgru_persistent(
    const float* __restrict__ h0,     const float* __restrict__ v0,
    const float* __restrict__ dU0,    const float* __restrict__ tE0,
    const float* __restrict__ te0,
    const float* __restrict__ h2h_w,  const float* __restrict__ h2h_b,
    const float* __restrict__ lnh_g,  const float* __restrict__ lnh_b,
    const float* __restrict__ h2mod_w,const float* __restrict__ h2mod_b,
    const float* __restrict__ mod2h_w,const float* __restrict__ mod2h_b,
    const float* __restrict__ alpha_p,const float* __restrict__ tau_p,
    const float* __restrict__ dec_w,  const float* __restrict__ dec_b,
    float* __restrict__ out,          float* __restrict__ ws)
{
  const int tid = threadIdx.x;
  const int b   = blockIdx.x & 7;    // consecutive blockIdx -> XCD round-robin
  const int ir  = blockIdx.x >> 3;   // row-group 0..31
  const int i0  = ir << 4;
  const int il  = tid >> 5;
  const int m   = tid & 31;
  const int gi  = i0 + il;

  const float* Wx = ws + OFF_WX;
  float* colvG    = ws + OFF_COLV;
  unsigned* flags = (unsigned*)(ws + OFF_FLAGS);

  __shared__ float nh_s[2][HH];        // nh double buffer by parity
  __shared__ float te_s[HH];           // block-local te (redundant)
  __shared__ float hmw_s[RR * HMW_P];  // staged h2mod_w, padded pitch
  __shared__ float dec_s[16 * HH];     // staged dec_w rows [i0, i0+16)  (32 KB)
  __shared__ float mp_s[RR];
  __shared__ float rsm_s[4];
  __shared__ float red_s[2][8];

  const float a_sp  = log1pf(__expf(alpha_p[0]));
  const float inv_a = 1.0f / (a_sp + 1e-8f);
  const float tau   = 1.0f / (1.0f + __expf(-tau_p[0]));
  const float c1t   = 1.0f - tau;

  // ---- register-resident state: dU, tE, w_dv row, w_low row, clip bounds ----
  float4 dUr[4], tEr[4], Wdvr[4], wlo[4], upr[4], lor[4];
  {
    const size_t rowoff = ((size_t)b * HH + gi) * HH;
    const size_t whioff = (size_t)(HH + gi) * HH;
    const size_t wlooff = (size_t)gi * HH;
#pragma unroll
    for (int q = 0; q < 4; ++q) {
      const int J = m + 32*q;
      dUr[q] = *reinterpret_cast<const float4*>(dU0 + rowoff + 4*J);
      tEr[q] = *reinterpret_cast<const float4*>(tE0 + rowoff + 4*J);
      wlo[q] = *reinterpret_cast<const float4*>(h2h_w + wlooff + 4*J);
      const float4 w = *reinterpret_cast<const float4*>(h2h_w + whioff + 4*J);
      Wdvr[q] = w;
      float4 u, l;
      u.x =  fmaxf(1.0f - w.x, 0.0f) * inv_a;  l.x = -fmaxf(1.0f + w.x, 0.0f) * inv_a;
      u.y =  fmaxf(1.0f - w.y, 0.0f) * inv_a;  l.y = -fmaxf(1.0f + w.y, 0.0f) * inv_a;
      u.z =  fmaxf(1.0f - w.z, 0.0f) * inv_a;  l.z = -fmaxf(1.0f + w.z, 0.0f) * inv_a;
      u.w =  fmaxf(1.0f - w.w, 0.0f) * inv_a;  l.w = -fmaxf(1.0f + w.w, 0.0f) * inv_a;
      upr[q] = u; lor[q] = l;
    }
  }

  // ---- per-thread constants in registers ----
  const float rgz = lnh_g[tid],      rbz = lnh_b[tid];
  const float rgd = lnh_g[HH + tid], rbd = lnh_b[HH + tid];
  const float hbl = h2h_b[gi], hbh = h2h_b[HH + gi];
  const float hmb = h2mod_b[tid >> 4];
  const float mw0 = (tid < RR) ? mod2h_w[tid]        : 0.0f;
  const float mw1 = (tid < RR) ? mod2h_w[RR + tid]   : 0.0f;
  const float mw2 = (tid < RR) ? mod2h_w[2*RR + tid] : 0.0f;
  const float mb0 = mod2h_b[0], mb1 = mod2h_b[1], mb2 = mod2h_b[2];
  const float dbc = dec_b[gi];                 // decode bias for owned out col
  float vreg = v0[b*HH + tid];

  // ---- prologue: stage LDS (incl. dec_w rows), compute Wh(0), post to buf 0 ----
  nh_s[1][tid] = h0[b*HH + tid];     // "prev" for t=0
  te_s[tid]    = te0[b*HH + tid];
  for (int idx = tid; idx < RR*HH; idx += 512)
    hmw_s[(idx >> 9)*HMW_P + (idx & 511)] = h2mod_w[idx];
  {
    const float4* src = reinterpret_cast<const float4*>(dec_w + (size_t)i0 * HH);
    float4* dst = reinterpret_cast<float4*>(dec_s);
    for (int idx = tid; idx < 16*HH/4; idx += 512) dst[idx] = src[idx];
  }
  __syncthreads();

  gemv_step<false>(gi, m, dUr, tEr, Wdvr, wlo, upr, lor,
                   0.0f, c1t, 0.0f, a_sp, hbl, hbh,
                   nh_s[1], te_s, colvG + 0*BB*H2 + b*H2);

  float wxz = Wx[(size_t)(0*BB + b)*H2 + tid];
  float wxd = Wx[(size_t)(0*BB + b)*H2 + HH + tid];

  const float4* drow4 = reinterpret_cast<const float4*>(dec_s + (size_t)il * HH);

  unsigned seq = 0;
  for (int t = 0; t < TT; ++t) {
    const int cur = t & 1;
    ++seq;

    // ---- barrier (proven R11 protocol: flag store, wave-0 poll) ----
    __syncthreads();                   // each wave drains its stores (incl. posts)
    asm volatile("s_waitcnt vmcnt(0)" ::: "memory");
    if (tid == 0)
      __hip_atomic_store(&flags[b*32 + ir], seq, RLX, AGENT);
    if (tid < 64) {                    // wave 0: poll all 32 flags immediately
      for (;;) {
        unsigned v = (tid < 32) ? __hip_atomic_load(&flags[b*32 + tid], RLX, AGENT) : seq;
        if (__all(v >= seq)) break;
        __builtin_amdgcn_s_sleep(1);
      }
    }
    __syncthreads();                   // all posts of buf[cur] visible

    // ---- issue coherent gather loads (no wait yet) ----
    float whz, whd;
    {
      const float* pz = &colvG[cur*BB*H2 + b*H2 + tid];
      const float* pd = pz + HH;
      asm volatile("global_load_dword %0, %1, off sc0 sc1" : "=v"(whz) : "v"(pz));
      asm volatile("global_load_dword %0, %1, off sc0 sc1" : "=v"(whd) : "v"(pd));
    }

    // ---- decode step t-1 under the gather latency (LDS/VALU only, store deferred) ----
    float dacc = 0.0f;
    if (t > 0) {
      const float4* nh4p = reinterpret_cast<const float4*>(nh_s[1 - cur]);
#pragma unroll
      for (int q = 0; q < 4; ++q) {
        const int J = m + 32*q;
        dacc += d4(drow4[J], nh4p[J]);
      }
#pragma unroll
      for (int off = 16; off >= 1; off >>= 1) dacc += __shfl_xor(dacc, off);
    }
    __builtin_amdgcn_sched_barrier(0);           // pin decode above the waitcnt
    asm volatile("s_waitcnt vmcnt(0)" : "+v"(whz), "+v"(whd) :: "memory");
    if (t > 0 && m == 0)                          // store after wait (drains next step)
      out[(size_t)((t-1)*BB + b)*OO + gi] = dacc + dbc;

    // ---- LN stats over 1024 (block-redundant, bitwise identical) ----
    float s1 = whz + whd, s2 = whz*whz + whd*whd;
#pragma unroll
    for (int off = 32; off >= 1; off >>= 1) {
      s1 += __shfl_xor(s1, off);
      s2 += __shfl_xor(s2, off);
    }
    if ((tid & 63) == 0) { red_s[0][tid >> 6] = s1; red_s[1][tid >> 6] = s2; }
    __syncthreads();
    s1 = 0.0f; s2 = 0.0f;
#pragma unroll
    for (int w = 0; w < 8; ++w) { s1 += red_s[0][w]; s2 += red_s[1][w]; }
    const float mu   = s1 * (1.0f / H2);
    const float var  = s2 * (1.0f / H2) - mu * mu;
    const float rstd = rsqrtf(var + 1e-5f);

    // ---- LN + gate + v + nh (thread owns element tid) ----
    const float yz = (whz - mu)*rstd*rgz + rbz + wxz;
    const float yd = (whd - mu)*rstd*rgd + rbd + wxd;
    const float z  = 1.0f / (1.0f + __expf(-yz));
    vreg = vreg + z * (yd - vreg);
    const float nh = fmaxf(vreg, 0.0f);
    nh_s[cur][tid] = nh;

    if (t == TT - 1) {                 // final step: decode own row, then exit
      __syncthreads();
      const float4* nh4p = reinterpret_cast<const float4*>(nh_s[cur]);
      float acc = 0.0f;
#pragma unroll
      for (int q = 0; q < 4; ++q) {
        const int J = m + 32*q;
        acc += d4(drow4[J], nh4p[J]);
      }
#pragma unroll
      for (int off = 16; off >= 1; off >>= 1) acc += __shfl_xor(acc, off);
      if (m == 0) out[(size_t)(t*BB + b)*OO + gi] = acc + dbc;
      return;
    }

    // prefetch next step's Wx under upcoming latency
    wxz = Wx[(size_t)((t+1)*BB + b)*H2 + tid];
    wxd = Wx[(size_t)((t+1)*BB + b)*H2 + HH + tid];
    __syncthreads();                   // nh_s[cur] ready

    // ---- modulator GEMV from LDS (redundant): r = tid>>4, kk = tid&15 ----
    {
      const int r = tid >> 4, kk = tid & 15;
      float part = 0.0f;
#pragma unroll
      for (int j = 0; j < 32; ++j)
        part += hmw_s[r*HMW_P + kk + 16*j] * nh_s[cur][kk + 16*j];
#pragma unroll
      for (int off = 8; off >= 1; off >>= 1) part += __shfl_xor(part, off);
      if (kk == 0) mp_s[r] = fmaxf(part + hmb, 0.0f);
    }
    __syncthreads();
    if (tid < 64) {                    // wave 0: r/s/m 3x32 dots
      const float mp = (tid < RR) ? mp_s[tid] : 0.0f;
      float a0 = mw0*mp, a1 = mw1*mp, a2 = mw2*mp;
#pragma unroll
      for (int off = 16; off >= 1; off >>= 1) {
        a0 += __shfl_xor(a0, off);
        a1 += __shfl_xor(a1, off);
        a2 += __shfl_xor(a2, off);
      }
      if (tid == 0) {
        rsm_s[0] = 1.0f / (1.0f + __expf(-(a0 + mb0)));
        rsm_s[1] = 1.0f / (1.0f + __expf(-(a1 + mb1)));
        rsm_s[2] = a2 + mb2;
      }
    }
    __syncthreads();
    const float r_b = rsm_s[0];
    const float s_b = rsm_s[1];
    const float c2t = tau * rsm_s[2];

    // ---- te update (redundant): te_n = (1-r)te + r*h_prev ----
    te_s[tid] += r_b * (nh_s[1 - cur][tid] - te_s[tid]);
    __syncthreads();

    // ---- state update + Wh GEMV for next step, post to buf[1-cur] ----
    gemv_step<true>(gi, m, dUr, tEr, Wdvr, wlo, upr, lor,
                    s_b, c1t, c2t, a_sp, hbl, hbh,
                    nh_s[cur], te_s, colvG + (1 - cur)*BB*H2 + b*H2);
  }
}

// ---------------- tiled fp32 GEMM: C[M][N] = A[M][K=512] . W[N][K]^T + bias ----------------
#define GBM 32
#define GBN 32
#define GBK 32
__global__ __launch_bounds__(256) void gemm_tn(
    const float* __restrict__ A, const float* __restrict__ W,
    const float* __restrict__ bias, float* __restrict__ C,
    int M, int N)
{
  const int K = 512;
  const int nbn = N / GBN;
  const int m0 = (blockIdx.x / nbn) * GBM;
  const int n0 = (blockIdx.x % nbn) * GBN;
  const int tid = threadIdx.x;
  const int tx = tid & 15;   // n: tx*2
  const int ty = tid >> 4;   // m: ty*2
  const int lr = tid >> 3;   // 0..31 (load row)
  const int lc = tid & 7;    // 0..7  (k float4)
  __shared__ float As[GBK][36];
  __shared__ float Ws[GBK][36];
  float acc[2][2] = {};
  for (int kc = 0; kc < K; kc += GBK) {
    const float4 a0 = *reinterpret_cast<const float4*>(A + (size_t)(m0 + lr)*K + kc + lc*4);
    const float4 w0 = *reinterpret_cast<const float4*>(W + (size_t)(n0 + lr)*K + kc + lc*4);
    __syncthreads();
    As[lc*4+0][lr] = a0.x; As[lc*4+1][lr] = a0.y; As[lc*4+2][lr] = a0.z; As[lc*4+3][lr] = a0.w;
    Ws[lc*4+0][lr] = w0.x; Ws[lc*4+1][lr] = w0.y; Ws[lc*4+2][lr] = w0.z; Ws[lc*4+3][lr] = w0.w;
    __syncthreads();
#pragma unroll
    for (int k = 0; k < GBK; ++k) {
      const float2 am = *reinterpret_cast<const float2*>(&As[k][ty*2]);
      const float2 wn = *reinterpret_cast<const float2*>(&Ws[k][tx*2]);
      acc[0][0] += am.x*wn.x; acc[0][1] += am.x*wn.y;
      acc[1][0] += am.y*wn.x; acc[1][1] += am.y*wn.y;
    }
  }
  const float b0 = bias[n0 + tx*2], b1 = bias[n0 + tx*2 + 1];
  C[(size_t)(m0 + ty*2 + 0)*N + n0 + tx*2]     = acc[0][0] + b0;
  C[(size_t)(m0 + ty*2 + 0)*N + n0 + tx*2 + 1] = acc[0][1] + b1;
  C[(size_t)(m0 + ty*2 + 1)*N + n0 + tx*2]     = acc[1][0] + b0;
  C[(size_t)(m0 + ty*2 + 1)*N + n0 + tx*2 + 1] = acc[1][1] + b1;
}

// ---------------- in-place row LayerNorm (256 rows) + zero barrier flags ----------------
__global__ __launch_bounds__(256) void ln_apply(
    float* __restrict__ Wp, const float* __restrict__ g, const float* __restrict__ b,
    unsigned* __restrict__ flags)
{
  const int row = blockIdx.x;
  const int tid = threadIdx.x;
  if (row == 0) flags[tid] = 0u;     // 256 barrier flags (seq starts at 1)
  float* rp = Wp + (size_t)row * H2;
  float4 v = *reinterpret_cast<const float4*>(rp + tid*4);
  float s1 = v.x + v.y + v.z + v.w;
  float s2 = v.x*v.x + v.y*v.y + v.z*v.z + v.w*v.w;
#pragma unroll
  for (int off = 32; off >= 1; off >>= 1) {
    s1 += __shfl_xor(s1, off);
    s2 += __shfl_xor(s2, off);
  }
  __shared__ float red[2][4];
  if ((tid & 63) == 0) { red[0][tid >> 6] = s1; red[1][tid >> 6] = s2; }
  __syncthreads();
  s1 = red[0][0] + red[0][1] + red[0][2] + red[0][3];
  s2 = red[1][0] + red[1][1] + red[1][2] + red[1][3];
  const float mu   = s1 * (1.0f / H2);
  const float var  = s2 * (1.0f / H2) - mu * mu;
  const float rstd = rsqrtf(var + 1e-5f);
  const float4 gv = *reinterpret_cast<const float4*>(g + tid*4);
  const float4 bv = *reinterpret_cast<const float4*>(b + tid*4);
  v.x = gv.x*(v.x - mu)*rstd + bv.x;
  v.y = gv.y*(v.y - mu)*rstd + bv.y;
  v.z = gv.z*(v.z - mu)*rstd + bv.z;
  v.w = gv.w*(v.w - mu)*rstd + bv.w;
  *reinterpret_cast<float4*>(rp + tid*4) = v;
}

extern "C" void kernel_launch(void* const* d_in, const int* in_sizes, int n_in,
                              void* d_out, int out_size, void* d_ws, size_t ws_size,
                              hipStream_t stream) {
  (void)in_sizes; (void)n_in; (void)out_size; (void)ws_size;
  const float* x        = (const float*)d_in[0];
  const float* h0       = (const float*)d_in[1];
  const float* v0       = (const float*)d_in[2];
  const float* dU0      = (const float*)d_in[3];
  const float* te0      = (const float*)d_in[4];   // trace_e0
  const float* tE0      = (const float*)d_in[5];   // trace_E0
  const float* x2h_w    = (const float*)d_in[6];
  const float* x2h_b    = (const float*)d_in[7];
  const float* h2h_w    = (const float*)d_in[8];
  const float* h2h_b    = (const float*)d_in[9];
  const float* lnx_g    = (const float*)d_in[10];
  const float* lnx_b    = (const float*)d_in[11];
  const float* lnh_g    = (const float*)d_in[12];
  const float* lnh_b    = (const float*)d_in[13];
  const float* h2mod_w  = (const float*)d_in[14];
  const float* h2mod_b  = (const float*)d_in[15];
  const float* mod2h_w  = (const float*)d_in[16];
  const float* mod2h_b  = (const float*)d_in[17];
  const float* alpha    = (const float*)d_in[18];
  const float* tau_U    = (const float*)d_in[19];
  const float* dec_w    = (const float*)d_in[20];
  const float* dec_b    = (const float*)d_in[21];

  float* ws = (float*)d_ws;

  // 1) Wx pre-LN GEMM: [256 x 1024] = x . x2h_w^T  (256 blocks)
  gemm_tn<<<(TT*BB/GBM) * (H2/GBN), 256, 0, stream>>>(x, x2h_w, x2h_b,
                                                      ws + OFF_WX, TT*BB, H2);
  // 2) LN in place (256 rows) + zero barrier flags
  ln_apply<<<TT*BB, 256, 0, stream>>>(ws + OFF_WX, lnx_g, lnx_b,
                                      (unsigned*)(ws + OFF_FLAGS));

  // 3) persistent recurrent kernel (decode hidden under the coherent-gather latency)
  sgru_persistent<<<256, 512, 0, stream>>>(h0, v0, dU0, tE0, te0,
                                           h2h_w, h2h_b, lnh_g, lnh_b,
                                           h2mod_w, h2mod_b, mod2h_w, mod2h_b,
                                           alpha, tau_U, dec_w, dec_b,
                                           (float*)d_out, ws);
}

// Round 17
// 171.335 us; speedup vs baseline: 1.0374x; 1.0374x over previous
//
#include <hip/hip_runtime.h>

// Problem dims
#define TT 32
#define BB 8
#define DD 512
#define HH 512
#define RR 32
#define OO 512
#define H2 1024

typedef unsigned int uint;

// d_ws float-index offsets
#define OFF_WX    0        // [TT*BB][H2]   262144  (pre-LN then LN'd in place)
#define OFF_COLV  393216   // [2][BB][H2]    16384  (coherent Wh exchange)
#define OFF_FLAGS 409600   // 256 u32 barrier flags

#define AGENT __HIP_MEMORY_SCOPE_AGENT
#define RLX   __ATOMIC_RELAXED

#define HMW_P 528   // 528 % 32 == 16 -> hmw LDS accesses are exact 2-way (free)

__device__ __forceinline__ void st_coh(float* p, float v) {
  __hip_atomic_store(p, v, RLX, AGENT);
}
__device__ __forceinline__ float ld_coh(const float* p) {
  return __hip_atomic_load(const_cast<float*>(p), RLX, AGENT);
}
__device__ __forceinline__ float d4(const float4& a, const float4& b) {
  return a.x*b.x + a.y*b.y + a.z*b.z + a.w*b.w;
}

// ---------------- fused state-update + plast + Wh GEMV -> coherent post ----------------
// Row mapping: il = tid>>5 (row 0..15 of block), m = tid&31, elem j = 4*(m+32q)+c.
template<bool UPDATE>
__device__ __forceinline__ void gemv_step(
    int gi, int m,
    float4 (&dUr)[4], float4 (&tEr)[4],
    const float4 (&Wdvr)[4], const float4 (&wlo)[4],
    const float4 (&upr)[4], const float4 (&lor)[4],
    float s_b, float c1t, float c2t, float a_sp, float hbl, float hbh,
    const float* nh_s, const float* te_s,
    float* post)  // colvG + parity*BB*H2 + b*H2
{
  const float nh_i = nh_s[gi];
  const float te_i = UPDATE ? te_s[gi] : 0.0f;
  const float4* nh4 = reinterpret_cast<const float4*>(nh_s);
  const float4* te4 = reinterpret_cast<const float4*>(te_s);
  float plast = 0.0f, gdv = 0.0f, glo = 0.0f;
#pragma unroll
  for (int q = 0; q < 4; ++q) {
    const int J = m + 32*q;
    const float4 h4 = nh4[J];
    if (UPDATE) {
      const float4 t4 = te4[J];
#define SGRU_UPD(C) { \
      float o   = nh_i * t4.C - h4.C * te_i;                /* outer - outer^T    */ \
      float tEn = tEr[q].C + s_b * (o - tEr[q].C);          /* (1-s)tE + s*o      */ \
      tEr[q].C  = tEn;                                                               \
      float d   = c1t * dUr[q].C + c2t * tEn;               /* (1-tau)dU+tau*m*tE */ \
      d = fminf(d, upr[q].C); d = fmaxf(d, lor[q].C);       /* clip               */ \
      dUr[q].C  = d;                                                                 \
      plast = fmaf(d, h4.C, plast); }
      SGRU_UPD(x) SGRU_UPD(y) SGRU_UPD(z) SGRU_UPD(w)
#undef SGRU_UPD
    } else {
      plast += d4(dUr[q], h4);
    }
    gdv += d4(Wdvr[q], h4);
    glo += d4(wlo[q],  h4);
  }
#pragma unroll
  for (int off = 16; off >= 1; off >>= 1) {
    plast += __shfl_xor(plast, off);
    gdv   += __shfl_xor(gdv, off);
    glo   += __shfl_xor(glo, off);
  }
  if (m == 0) {
    st_coh(&post[gi],      glo + hbl);                    // low col gi
    st_coh(&post[HH + gi], gdv + hbh + a_sp * plast);     // high col HH+gi
  }
}

// ---------------- persistent recurrent kernel: 1 barrier/step, slack-fused decode ----------------
__global__ __launch_bounds__(512, 1) void sgru_persistent(
    const float* __restrict__ h0,     const float* __restrict__ v0,
    const float* __restrict__ dU0,    const float* __restrict__ tE0,
    const float* __restrict__ te0,
    const float* __restrict__ h2h_w,  const float* __restrict__ h2h_b,
    const float* __restrict__ lnh_g,  const float* __restrict__ lnh_b,
    const float* __restrict__ h2mod_w,const float* __restrict__ h2mod_b,
    const float* __restrict__ mod2h_w,const float* __restrict__ mod2h_b,
    const float* __restrict__ alpha_p,const float* __restrict__ tau_p,
    const float* __restrict__ dec_w,  const float* __restrict__ dec_b,
    float* __restrict__ out,          float* __restrict__ ws)
{
  const int tid = threadIdx.x;
  const int b   = blockIdx.x & 7;    // consecutive blockIdx -> XCD round-robin
  const int ir  = blockIdx.x >> 3;   // row-group 0..31
  const int i0  = ir << 4;
  const int il  = tid >> 5;
  const int m   = tid & 31;
  const int gi  = i0 + il;

  const float* Wx = ws + OFF_WX;
  float* colvG    = ws + OFF_COLV;
  unsigned* flags = (unsigned*)(ws + OFF_FLAGS);

  __shared__ float nh_s[2][HH];        // nh double buffer by parity
  __shared__ float te_s[HH];           // block-local te (redundant)
  __shared__ float hmw_s[RR * HMW_P];  // staged h2mod_w, padded pitch
  __shared__ float dec_s[16 * HH];     // staged dec_w rows [i0, i0+16)  (32 KB)
  __shared__ float mp_s[RR];
  __shared__ float rsm_s[4];
  __shared__ float red_s[2][8];

  const float a_sp  = log1pf(__expf(alpha_p[0]));
  const float inv_a = 1.0f / (a_sp + 1e-8f);
  const float tau   = 1.0f / (1.0f + __expf(-tau_p[0]));
  const float c1t   = 1.0f - tau;

  // ---- register-resident state: dU, tE, w_dv row, w_low row, clip bounds ----
  float4 dUr[4], tEr[4], Wdvr[4], wlo[4], upr[4], lor[4];
  {
    const size_t rowoff = ((size_t)b * HH + gi) * HH;
    const size_t whioff = (size_t)(HH + gi) * HH;
    const size_t wlooff = (size_t)gi * HH;
#pragma unroll
    for (int q = 0; q < 4; ++q) {
      const int J = m + 32*q;
      dUr[q] = *reinterpret_cast<const float4*>(dU0 + rowoff + 4*J);
      tEr[q] = *reinterpret_cast<const float4*>(tE0 + rowoff + 4*J);
      wlo[q] = *reinterpret_cast<const float4*>(h2h_w + wlooff + 4*J);
      const float4 w = *reinterpret_cast<const float4*>(h2h_w + whioff + 4*J);
      Wdvr[q] = w;
      float4 u, l;
      u.x =  fmaxf(1.0f - w.x, 0.0f) * inv_a;  l.x = -fmaxf(1.0f + w.x, 0.0f) * inv_a;
      u.y =  fmaxf(1.0f - w.y, 0.0f) * inv_a;  l.y = -fmaxf(1.0f + w.y, 0.0f) * inv_a;
      u.z =  fmaxf(1.0f - w.z, 0.0f) * inv_a;  l.z = -fmaxf(1.0f + w.z, 0.0f) * inv_a;
      u.w =  fmaxf(1.0f - w.w, 0.0f) * inv_a;  l.w = -fmaxf(1.0f + w.w, 0.0f) * inv_a;
      upr[q] = u; lor[q] = l;
    }
  }

  // ---- per-thread constants in registers ----
  const float rgz = lnh_g[tid],      rbz = lnh_b[tid];
  const float rgd = lnh_g[HH + tid], rbd = lnh_b[HH + tid];
  const float hbl = h2h_b[gi], hbh = h2h_b[HH + gi];
  const float hmb = h2mod_b[tid >> 4];
  const float mw0 = (tid < RR) ? mod2h_w[tid]        : 0.0f;
  const float mw1 = (tid < RR) ? mod2h_w[RR + tid]   : 0.0f;
  const float mw2 = (tid < RR) ? mod2h_w[2*RR + tid] : 0.0f;
  const float mb0 = mod2h_b[0], mb1 = mod2h_b[1], mb2 = mod2h_b[2];
  const float dbc = dec_b[gi];                 // decode bias for owned out col
  float vreg = v0[b*HH + tid];

  // ---- prologue: stage LDS (incl. dec_w rows), compute Wh(0), post to buf 0 ----
  nh_s[1][tid] = h0[b*HH + tid];     // "prev" for t=0
  te_s[tid]    = te0[b*HH + tid];
  for (int idx = tid; idx < RR*HH; idx += 512)
    hmw_s[(idx >> 9)*HMW_P + (idx & 511)] = h2mod_w[idx];
  {
    const float4* src = reinterpret_cast<const float4*>(dec_w + (size_t)i0 * HH);
    float4* dst = reinterpret_cast<float4*>(dec_s);
    for (int idx = tid; idx < 16*HH/4; idx += 512) dst[idx] = src[idx];
  }
  __syncthreads();

  gemv_step<false>(gi, m, dUr, tEr, Wdvr, wlo, upr, lor,
                   0.0f, c1t, 0.0f, a_sp, hbl, hbh,
                   nh_s[1], te_s, colvG + 0*BB*H2 + b*H2);

  float wxz = Wx[(size_t)(0*BB + b)*H2 + tid];
  float wxd = Wx[(size_t)(0*BB + b)*H2 + HH + tid];

  const float4* drow4 = reinterpret_cast<const float4*>(dec_s + (size_t)il * HH);

  unsigned seq = 0;
  for (int t = 0; t < TT; ++t) {
    const int cur = t & 1;
    ++seq;

    // ---- barrier with slack-fused decode ----
    __syncthreads();                   // each wave drains its stores (incl. posts)
    asm volatile("s_waitcnt vmcnt(0)" ::: "memory");
    if (tid == 0)
      __hip_atomic_store(&flags[b*32 + ir], seq, RLX, AGENT);
    if (t > 0) {                       // decode step t-1 while flags propagate
      const float4* nh4 = reinterpret_cast<const float4*>(nh_s[1 - cur]);
      float acc = 0.0f;
#pragma unroll
      for (int q = 0; q < 4; ++q) {
        const int J = m + 32*q;
        acc += d4(drow4[J], nh4[J]);
      }
#pragma unroll
      for (int off = 16; off >= 1; off >>= 1) acc += __shfl_xor(acc, off);
      if (m == 0) out[(size_t)((t-1)*BB + b)*OO + gi] = acc + dbc;
    }
    if (tid < 64) {                    // wave 0: poll all 32 flags
      for (;;) {
        unsigned v = (tid < 32) ? __hip_atomic_load(&flags[b*32 + tid], RLX, AGENT) : seq;
        if (__all(v >= seq)) break;
        __builtin_amdgcn_s_sleep(1);
      }
    }
    __syncthreads();                   // all posts of buf[cur] visible

    // ---- gather the 2 Wh values this thread needs ----
    const float whz = ld_coh(&colvG[cur*BB*H2 + b*H2 + tid]);
    const float whd = ld_coh(&colvG[cur*BB*H2 + b*H2 + HH + tid]);

    // ---- LN stats over 1024 (block-redundant, bitwise identical) ----
    float s1 = whz + whd, s2 = whz*whz + whd*whd;
#pragma unroll
    for (int off = 32; off >= 1; off >>= 1) {
      s1 += __shfl_xor(s1, off);
      s2 += __shfl_xor(s2, off);
    }
    if ((tid & 63) == 0) { red_s[0][tid >> 6] = s1; red_s[1][tid >> 6] = s2; }
    __syncthreads();
    s1 = 0.0f; s2 = 0.0f;
#pragma unroll
    for (int w = 0; w < 8; ++w) { s1 += red_s[0][w]; s2 += red_s[1][w]; }
    const float mu   = s1 * (1.0f / H2);
    const float var  = s2 * (1.0f / H2) - mu * mu;
    const float rstd = rsqrtf(var + 1e-5f);

    // ---- LN + gate + v + nh (thread owns element tid) ----
    const float yz = (whz - mu)*rstd*rgz + rbz + wxz;
    const float yd = (whd - mu)*rstd*rgd + rbd + wxd;
    const float z  = 1.0f / (1.0f + __expf(-yz));
    vreg = vreg + z * (yd - vreg);
    const float nh = fmaxf(vreg, 0.0f);
    nh_s[cur][tid] = nh;

    if (t == TT - 1) {                 // final step: decode own row, then exit
      __syncthreads();
      const float4* nh4 = reinterpret_cast<const float4*>(nh_s[cur]);
      float acc = 0.0f;
#pragma unroll
      for (int q = 0; q < 4; ++q) {
        const int J = m + 32*q;
        acc += d4(drow4[J], nh4[J]);
      }
#pragma unroll
      for (int off = 16; off >= 1; off >>= 1) acc += __shfl_xor(acc, off);
      if (m == 0) out[(size_t)(t*BB + b)*OO + gi] = acc + dbc;
      return;
    }

    // prefetch next step's Wx under upcoming latency
    wxz = Wx[(size_t)((t+1)*BB + b)*H2 + tid];
    wxd = Wx[(size_t)((t+1)*BB + b)*H2 + HH + tid];
    __syncthreads();                   // nh_s[cur] ready

    // ---- modulator GEMV from LDS (redundant): r = tid>>4, kk = tid&15 ----
    {
      const int r = tid >> 4, kk = tid & 15;
      float part = 0.0f;
#pragma unroll
      for (int j = 0; j < 32; ++j)
        part += hmw_s[r*HMW_P + kk + 16*j] * nh_s[cur][kk + 16*j];
#pragma unroll
      for (int off = 8; off >= 1; off >>= 1) part += __shfl_xor(part, off);
      if (kk == 0) mp_s[r] = fmaxf(part + hmb, 0.0f);
    }
    __syncthreads();
    if (tid < 64) {                    // wave 0: r/s/m 3x32 dots
      const float mp = (tid < RR) ? mp_s[tid] : 0.0f;
      float a0 = mw0*mp, a1 = mw1*mp, a2 = mw2*mp;
#pragma unroll
      for (int off = 16; off >= 1; off >>= 1) {
        a0 += __shfl_xor(a0, off);
        a1 += __shfl_xor(a1, off);
        a2 += __shfl_xor(a2, off);
      }
      if (tid == 0) {
        rsm_s[0] = 1.0f / (1.0f + __expf(-(a0 + mb0)));
        rsm_s[1] = 1.0f / (1.0f + __expf(-(a1 + mb1)));
        rsm_s[2] = a2 + mb2;
      }
    }
    __syncthreads();
    const float r_b = rsm_s[0];
    const float s_b = rsm_s[1];
    const float c2t = tau * rsm_s[2];

    // ---- te update (redundant): te_n = (1-r)te + r*h_prev ----
    te_s[tid] += r_b * (nh_s[1 - cur][tid] - te_s[tid]);
    __syncthreads();

    // ---- state update + Wh GEMV for next step, post to buf[1-cur] ----
    gemv_step<true>(gi, m, dUr, tEr, Wdvr, wlo, upr, lor,
                    s_b, c1t, c2t, a_sp, hbl, hbh,
                    nh_s[cur], te_s, colvG + (1 - cur)*BB*H2 + b*H2);
  }
}

// ---------------- tiled fp32 GEMM: C[M][N] = A[M][K=512] . W[N][K]^T + bias ----------------
#define GBM 32
#define GBN 32
#define GBK 32
__global__ __launch_bounds__(256) void gemm_tn(
    const float* __restrict__ A, const float* __restrict__ W,
    const float* __restrict__ bias, float* __restrict__ C,
    int M, int N)
{
  const int K = 512;
  const int nbn = N / GBN;
  const int m0 = (blockIdx.x / nbn) * GBM;
  const int n0 = (blockIdx.x % nbn) * GBN;
  const int tid = threadIdx.x;
  const int tx = tid & 15;   // n: tx*2
  const int ty = tid >> 4;   // m: ty*2
  const int lr = tid >> 3;   // 0..31 (load row)
  const int lc = tid & 7;    // 0..7  (k float4)
  __shared__ float As[GBK][36];
  __shared__ float Ws[GBK][36];
  float acc[2][2] = {};
  for (int kc = 0; kc < K; kc += GBK) {
    const float4 a0 = *reinterpret_cast<const float4*>(A + (size_t)(m0 + lr)*K + kc + lc*4);
    const float4 w0 = *reinterpret_cast<const float4*>(W + (size_t)(n0 + lr)*K + kc + lc*4);
    __syncthreads();
    As[lc*4+0][lr] = a0.x; As[lc*4+1][lr] = a0.y; As[lc*4+2][lr] = a0.z; As[lc*4+3][lr] = a0.w;
    Ws[lc*4+0][lr] = w0.x; Ws[lc*4+1][lr] = w0.y; Ws[lc*4+2][lr] = w0.z; Ws[lc*4+3][lr] = w0.w;
    __syncthreads();
#pragma unroll
    for (int k = 0; k < GBK; ++k) {
      const float2 am = *reinterpret_cast<const float2*>(&As[k][ty*2]);
      const float2 wn = *reinterpret_cast<const float2*>(&Ws[k][tx*2]);
      acc[0][0] += am.x*wn.x; acc[0][1] += am.x*wn.y;
      acc[1][0] += am.y*wn.x; acc[1][1] += am.y*wn.y;
    }
  }
  const float b0 = bias[n0 + tx*2], b1 = bias[n0 + tx*2 + 1];
  C[(size_t)(m0 + ty*2 + 0)*N + n0 + tx*2]     = acc[0][0] + b0;
  C[(size_t)(m0 + ty*2 + 0)*N + n0 + tx*2 + 1] = acc[0][1] + b1;
  C[(size_t)(m0 + ty*2 + 1)*N + n0 + tx*2]     = acc[1][0] + b0;
  C[(size_t)(m0 + ty*2 + 1)*N + n0 + tx*2 + 1] = acc[1][1] + b1;
}

// ---------------- in-place row LayerNorm (256 rows) + zero barrier flags ----------------
__global__ __launch_bounds__(256) void ln_apply(
    float* __restrict__ Wp, const float* __restrict__ g, const float* __restrict__ b,
    unsigned* __restrict__ flags)
{
  const int row = blockIdx.x;
  const int tid = threadIdx.x;
  if (row == 0) flags[tid] = 0u;     // 256 barrier flags (seq starts at 1)
  float* rp = Wp + (size_t)row * H2;
  float4 v = *reinterpret_cast<const float4*>(rp + tid*4);
  float s1 = v.x + v.y + v.z + v.w;
  float s2 = v.x*v.x + v.y*v.y + v.z*v.z + v.w*v.w;
#pragma unroll
  for (int off = 32; off >= 1; off >>= 1) {
    s1 += __shfl_xor(s1, off);
    s2 += __shfl_xor(s2, off);
  }
  __shared__ float red[2][4];
  if ((tid & 63) == 0) { red[0][tid >> 6] = s1; red[1][tid >> 6] = s2; }
  __syncthreads();
  s1 = red[0][0] + red[0][1] + red[0][2] + red[0][3];
  s2 = red[1][0] + red[1][1] + red[1][2] + red[1][3];
  const float mu   = s1 * (1.0f / H2);
  const float var  = s2 * (1.0f / H2) - mu * mu;
  const float rstd = rsqrtf(var + 1e-5f);
  const float4 gv = *reinterpret_cast<const float4*>(g + tid*4);
  const float4 bv = *reinterpret_cast<const float4*>(b + tid*4);
  v.x = gv.x*(v.x - mu)*rstd + bv.x;
  v.y = gv.y*(v.y - mu)*rstd + bv.y;
  v.z = gv.z*(v.z - mu)*rstd + bv.z;
  v.w = gv.w*(v.w - mu)*rstd + bv.w;
  *reinterpret_cast<float4*>(rp + tid*4) = v;
}

extern "C" void kernel_launch(void* const* d_in, const int* in_sizes, int n_in,
                              void* d_out, int out_size, void* d_ws, size_t ws_size,
                              hipStream_t stream) {
  (void)in_sizes; (void)n_in; (void)out_size; (void)ws_size;
  const float* x        = (const float*)d_in[0];
  const float* h0       = (const float*)d_in[1];
  const float* v0       = (const float*)d_in[2];
  const float* dU0      = (const float*)d_in[3];
  const float* te0      = (const float*)d_in[4];   // trace_e0
  const float* tE0      = (const float*)d_in[5];   // trace_E0
  const float* x2h_w    = (const float*)d_in[6];
  const float* x2h_b    = (const float*)d_in[7];
  const float* h2h_w    = (const float*)d_in[8];
  const float* h2h_b    = (const float*)d_in[9];
  const float* lnx_g    = (const float*)d_in[10];
  const float* lnx_b    = (const float*)d_in[11];
  const float* lnh_g    = (const float*)d_in[12];
  const float* lnh_b    = (const float*)d_in[13];
  const float* h2mod_w  = (const float*)d_in[14];
  const float* h2mod_b  = (const float*)d_in[15];
  const float* mod2h_w  = (const float*)d_in[16];
  const float* mod2h_b  = (const float*)d_in[17];
  const float* alpha    = (const float*)d_in[18];
  const float* tau_U    = (const float*)d_in[19];
  const float* dec_w    = (const float*)d_in[20];
  const float* dec_b    = (const float*)d_in[21];

  float* ws = (float*)d_ws;

  // 1) Wx pre-LN GEMM: [256 x 1024] = x . x2h_w^T  (256 blocks)
  gemm_tn<<<(TT*BB/GBM) * (H2/GBN), 256, 0, stream>>>(x, x2h_w, x2h_b,
                                                      ws + OFF_WX, TT*BB, H2);
  // 2) LN in place (256 rows) + zero barrier flags
  ln_apply<<<TT*BB, 256, 0, stream>>>(ws + OFF_WX, lnx_g, lnx_b,
                                      (unsigned*)(ws + OFF_FLAGS));

  // 3) persistent recurrent kernel (decode fused into barrier slack)
  sgru_persistent<<<256, 512, 0, stream>>>(h0, v0, dU0, tE0, te0,
                                           h2h_w, h2h_b, lnh_g, lnh_b,
                                           h2mod_w, h2mod_b, mod2h_w, mod2h_b,
                                           alpha, tau_U, dec_w, dec_b,
                                           (float*)d_out, ws);
}